// Round 15
// baseline (958.312 us; speedup 1.0000x reference)
//
#include <hip/hip_runtime.h>
#include <cstdint>
#include <cstddef>

typedef unsigned short u16;
typedef __attribute__((ext_vector_type(4))) float f32x4;
typedef __attribute__((ext_vector_type(4))) unsigned int u32x4;
typedef __attribute__((ext_vector_type(8))) short s16x8;

// ---------- bf16 helpers (bit-level) ----------
__device__ __forceinline__ float b2f(u16 u) {
  union { unsigned int i; float f; } x; x.i = ((unsigned int)u) << 16; return x.f;
}
__device__ __forceinline__ u16 f2b(float f) {
  union { float f; unsigned int i; } x; x.f = f;
  unsigned int i = x.i;
  i += 0x7fffu + ((i >> 16) & 1u);   // RNE
  return (u16)(i >> 16);
}

// ---------- MFMA via compiler builtin (correct + native AGPR C/D) ----------
__device__ __forceinline__ void mfma_bf16(f32x4& c, u32x4 a, u32x4 b) {
  union { u32x4 u; s16x8 s; } ua, ub;
  ua.u = a; ub.u = b;
  c = __builtin_amdgcn_mfma_f32_16x16x32_bf16(ua.s, ub.s, c, 0, 0, 0);
}

// ---------- async global->LDS, 16B per lane ----------
__device__ __forceinline__ void async_ld16(const u16* g, u16* l) {
  typedef __attribute__((address_space(1))) const unsigned int GU;
  typedef __attribute__((address_space(3))) unsigned int LU;
  __builtin_amdgcn_global_load_lds((GU*)g, (LU*)l, 16, 0, 0);
}

// =======================================================================
// Weight transpose + cast: in[K][ldin] f32 (use N cols) -> out[N][K] bf16
// =======================================================================
__global__ __launch_bounds__(256)
void transpose_cast_kernel(const float* __restrict__ in, u16* __restrict__ out,
                           int K, int N, int ldin) {
  __shared__ float tile[64][65];
  const int nb = N >> 6;
  const int bk = blockIdx.x / nb, bn = blockIdx.x % nb;
  const int k0 = bk * 64, n0 = bn * 64;
  const int tid = threadIdx.x;
#pragma unroll
  for (int p = 0; p < 16; ++p) {
    int idx = p * 256 + tid;
    int r = idx >> 6, c = idx & 63;
    tile[r][c] = in[(size_t)(k0 + r) * ldin + n0 + c];
  }
  __syncthreads();
#pragma unroll
  for (int p = 0; p < 16; ++p) {
    int idx = p * 256 + tid;
    int r = idx >> 6, c = idx & 63;
    out[(size_t)(n0 + r) * K + k0 + c] = f2b(tile[c][r]);
  }
}

// =======================================================================
// k transpose from combined qk buffer -> kt [(b*8+h)*256+d][t]
// grid = 2048, block 256
// =======================================================================
__global__ __launch_bounds__(256)
void transpose_k_kernel(const u16* __restrict__ qk, u16* __restrict__ kt) {
  __shared__ u16 tile[64][72];
  const int bid = blockIdx.x;
  const int dd = bid & 3, tt = (bid >> 2) & 31;
  const int h = (bid >> 7) & 7, b = bid >> 10;
  const int t0 = tt * 64, d0 = dd * 64;
  const int tid = threadIdx.x;
#pragma unroll
  for (int p = 0; p < 2; ++p) {
    int idx = p * 256 + tid;
    int r = idx >> 3, cq = (idx & 7) * 8;
    *(uint4*)&tile[r][cq] =
        *(const uint4*)&qk[(size_t)(b * 2048 + t0 + r) * 4096 + 2048 + h * 256 + d0 + cq];
  }
  __syncthreads();
#pragma unroll
  for (int p = 0; p < 2; ++p) {
    int idx = p * 256 + tid;
    int r = idx >> 3, cq = (idx & 7) * 8;
    union { u16 h8[8]; uint4 v4; } o;
#pragma unroll
    for (int j = 0; j < 8; ++j) o.h8[j] = tile[cq + j][r];
    *(uint4*)&kt[((size_t)(b * 8 + h) * 256 + d0 + r) * 2048 + t0 + cq] = o.v4;
  }
}

// =======================================================================
// RMSNorm over 2048 f32 -> bf16
// =======================================================================
__global__ __launch_bounds__(256)
void rmsnorm_cast_kernel(const float* __restrict__ x, const float* __restrict__ w,
                         u16* __restrict__ out) {
  const int row = blockIdx.x, tid = threadIdx.x;
  const float* xr = x + (size_t)row * 2048;
  float4 a = ((const float4*)xr)[tid * 2];
  float4 b = ((const float4*)xr)[tid * 2 + 1];
  float ss = a.x*a.x + a.y*a.y + a.z*a.z + a.w*a.w
           + b.x*b.x + b.y*b.y + b.z*b.z + b.w*b.w;
#pragma unroll
  for (int m = 32; m; m >>= 1) ss += __shfl_xor(ss, m);
  __shared__ float ps[4];
  if ((tid & 63) == 0) ps[tid >> 6] = ss;
  __syncthreads();
  const float sc = rsqrtf((ps[0] + ps[1] + ps[2] + ps[3]) * (1.0f / 2048.0f) + 1e-6f);
  const int base = tid * 8;
  const float vals[8] = {a.x, a.y, a.z, a.w, b.x, b.y, b.z, b.w};
  union { u16 h[8]; uint4 v4[2]; } o;
#pragma unroll
  for (int j = 0; j < 8; ++j) o.h[j] = f2b(vals[j] * sc * w[base + j]);
  *(uint4*)&out[(size_t)row * 2048 + base] = o.v4[0];
  *(uint4*)&out[(size_t)row * 2048 + base + 8] = o.v4[1];
}

// =======================================================================
// RMSNorm over 2048 bf16 -> bf16
// =======================================================================
__global__ __launch_bounds__(256)
void rmsnorm_bf16_kernel(const u16* __restrict__ x, const float* __restrict__ w,
                         u16* __restrict__ out) {
  const int row = blockIdx.x, tid = threadIdx.x;
  union { uint4 v4; u16 h[8]; } p;
  p.v4 = *(const uint4*)&x[(size_t)row * 2048 + tid * 8];
  float v[8];
  float ss = 0.f;
#pragma unroll
  for (int j = 0; j < 8; ++j) { v[j] = b2f(p.h[j]); ss += v[j] * v[j]; }
#pragma unroll
  for (int m = 32; m; m >>= 1) ss += __shfl_xor(ss, m);
  __shared__ float ps[4];
  if ((tid & 63) == 0) ps[tid >> 6] = ss;
  __syncthreads();
  const float sc = rsqrtf((ps[0] + ps[1] + ps[2] + ps[3]) * (1.0f / 2048.0f) + 1e-6f);
  union { u16 h[8]; uint4 v4; } o;
#pragma unroll
  for (int j = 0; j < 8; ++j) o.h[j] = f2b(v[j] * sc * w[tid * 8 + j]);
  *(uint4*)&out[(size_t)row * 2048 + tid * 8] = o.v4;
}

// =======================================================================
// RoPE tables
// =======================================================================
__global__ __launch_bounds__(256)
void rope_table_kernel(float* __restrict__ ct, float* __restrict__ st) {
  const int idx = blockIdx.x * 256 + threadIdx.x;
  const int t = idx >> 7, i = idx & 127;
  const float e = -(float)i * (0.0078125f * log2f(10000.0f));
  const float ang = (float)t * exp2f(e);
  ct[idx] = cosf(ang);
  st[idx] = sinf(ang);
}

// =======================================================================
// RoPE apply in-place on combined qk buffer [4096][4096]
// =======================================================================
__global__ __launch_bounds__(256)
void rope_apply_kernel(u16* __restrict__ x, const float* __restrict__ ct,
                       const float* __restrict__ st, int qoff, float scale) {
  const int gid = blockIdx.x * 256 + threadIdx.x;
  const int r = gid >> 8;
  const int rem = gid & 255;
  const int h = rem >> 5;
  const int i4 = (rem & 31) * 4;
  const int t = r & 2047;
  const size_t o1 = (size_t)r * 4096 + qoff + h * 256 + i4;
  union { ushort4 v; u16 h4[4]; } p1, p2, q1, q2;
  p1.v = *(ushort4*)&x[o1];
  p2.v = *(ushort4*)&x[o1 + 128];
  const float4 c = *(const float4*)&ct[t * 128 + i4];
  const float4 s = *(const float4*)&st[t * 128 + i4];
  const float cc[4] = {c.x, c.y, c.z, c.w};
  const float sn[4] = {s.x, s.y, s.z, s.w};
#pragma unroll
  for (int j = 0; j < 4; ++j) {
    float x1 = b2f(p1.h4[j]), x2 = b2f(p2.h4[j]);
    q1.h4[j] = f2b((x1 * cc[j] - x2 * sn[j]) * scale);
    q2.h4[j] = f2b((x2 * cc[j] + x1 * sn[j]) * scale);
  }
  *(ushort4*)&x[o1] = q1.v;
  *(ushort4*)&x[o1 + 128] = q2.v;
}

// =======================================================================
// GEMM v6 (proven dbuf + counted-vmcnt, 128x128, 4 blocks/CU, 2D XCD
// patches).  Now the ONLY GEMM: best measured (656 TF up/gate, r14).
// grid must equal 8*pm*pn with gw*pm == nbm and (8/gw)*pn == nbn.
// EPI: 1 bf16; 2 f32 acc+b2f(hsrc); 3 bf16 silu(acc)*b2f(hsrc); 4 bf16 acc+fsrc
// =======================================================================
template <int EPI>
__global__ __launch_bounds__(256, 4)
void gemm6(const u16* __restrict__ A, const u16* __restrict__ Bt,
           void* Cout, const float* fsrc, const u16* hsrc,
           int N, int K, int lda, int pm, int pn, int gw) {
  __shared__ __align__(16) char smem[2][16384];   // per buf: A 8KB | B 8KB
  const int tid = threadIdx.x;
  const int l = tid & 63, w = tid >> 6;
  const int lr = l & 15, hi = l >> 4;
  const int wm = w >> 1, wn = w & 1;
  const int xcd = blockIdx.x & 7;
  const int jj = blockIdx.x >> 3;
  const int gx = xcd % gw, gy = xcd / gw;
  const int bm = gx * pm + jj / pn;
  const int bn = gy * pn + jj % pn;
  const int nt = K >> 5;

  const u16* Ap[2]; const u16* Bp[2];
#pragma unroll
  for (int t = 0; t < 2; ++t) {
    int s = t * 256 + tid;
    int row = s >> 2, ch = (s & 3) ^ ((s >> 3) & 3);
    Ap[t] = A + (size_t)(bm * 128 + row) * lda + ch * 8;
    Bp[t] = Bt + (size_t)(bn * 128 + row) * K + ch * 8;
  }
  const int dst0 = (0 * 256 + w * 64) * 16;
  const int dst1 = (1 * 256 + w * 64) * 16;

  int aoff[4], boff[4];
#pragma unroll
  for (int f = 0; f < 4; ++f) {
    int ra = wm * 64 + f * 16 + lr;
    aoff[f] = (ra * 4 + (hi ^ ((ra >> 1) & 3))) * 16;
    int rb = wn * 64 + f * 16 + lr;
    boff[f] = 8192 + (rb * 4 + (hi ^ ((rb >> 1) & 3))) * 16;
  }

  f32x4 acc[4][4];
#pragma unroll
  for (int m = 0; m < 4; ++m)
#pragma unroll
    for (int n = 0; n < 4; ++n) acc[m][n] = (f32x4){0.f, 0.f, 0.f, 0.f};

#define SB __builtin_amdgcn_sched_barrier(0)
  auto stage = [&](int i, int s) {
    const int k0 = i * 32;
    async_ld16(Ap[0] + k0, (u16*)(smem[s] + dst0));
    async_ld16(Ap[1] + k0, (u16*)(smem[s] + dst1));
    async_ld16(Bp[0] + k0, (u16*)(smem[s] + 8192 + dst0));
    async_ld16(Bp[1] + k0, (u16*)(smem[s] + 8192 + dst1));
  };

  stage(0, 0);
  SB;
  for (int i = 0; i < nt; ++i) {
    const int cur = i & 1;
    const int ip = (i + 1 < nt) ? i + 1 : 0;     // tail: dead re-stage
    stage(ip, cur ^ 1);
    SB;
    asm volatile("s_waitcnt vmcnt(4)" ::: "memory");   // tile i landed
    SB;
    __builtin_amdgcn_s_barrier();
    SB;
    u32x4 af[4], bf[4];
#pragma unroll
    for (int f = 0; f < 4; ++f) af[f] = *(const u32x4*)(smem[cur] + aoff[f]);
#pragma unroll
    for (int f = 0; f < 4; ++f) bf[f] = *(const u32x4*)(smem[cur] + boff[f]);
    __builtin_amdgcn_s_setprio(1);
#pragma unroll
    for (int m = 0; m < 4; ++m)
#pragma unroll
      for (int n = 0; n < 4; ++n) mfma_bf16(acc[m][n], af[m], bf[n]);
    __builtin_amdgcn_s_setprio(0);
    SB;
    __builtin_amdgcn_s_barrier();    // raw: no vmcnt drain
    SB;
  }
#undef SB

  const size_t crow0 = (size_t)(bm * 128 + wm * 64);
  const int ccol0 = bn * 128 + wn * 64;
#pragma unroll
  for (int m = 0; m < 4; ++m)
#pragma unroll
    for (int n = 0; n < 4; ++n)
#pragma unroll
      for (int j2 = 0; j2 < 4; ++j2) {
        size_t r = crow0 + m * 16 + hi * 4 + j2;
        size_t c = (size_t)(ccol0 + n * 16 + lr);
        size_t idx = r * N + c;
        float a = acc[m][n][j2];
        if (EPI == 1) {
          ((u16*)Cout)[idx] = f2b(a);
        } else if (EPI == 2) {
          ((float*)Cout)[idx] = a + b2f(hsrc[idx]);
        } else if (EPI == 3) {
          float u = b2f(hsrc[idx]);
          ((u16*)Cout)[idx] = f2b(a / (1.0f + expf(-a)) * u);
        } else {
          ((u16*)Cout)[idx] = f2b(a + fsrc[idx]);
        }
      }
}

// =======================================================================
// Chunkwise retention scan (unchanged).
// =======================================================================
#define LGK 264
#define LGC 72
__global__ __launch_bounds__(512)
void retention_kernel(const u16* __restrict__ qk, const u16* __restrict__ kt,
                      const u16* __restrict__ v, u16* __restrict__ o) {
  __shared__ __align__(16) u16 ks[64 * LGK];
  __shared__ __align__(16) u16 stb[32 * LGK];
  __shared__ __align__(16) u16 ktd[256 * LGC];
  __shared__ __align__(16) u16 vts[32 * LGC];
  __shared__ __align__(16) u16 ab[64 * LGC];
  __shared__ float kdt[64];

  const int tid = threadIdx.x;
  const int l = tid & 63, w = tid >> 6;
  const int lr = l & 15, hi = l >> 4;
  const int wr = w >> 1;
  const int eb = w & 1;
  const int bid = blockIdx.x;
  const int g = bid & 15;
  const int sl = bid >> 4;
  const int hh = g & 7;
  const int b = g >> 3;
  const float gamma = 1.0f - exp2f(-5.0f - (float)hh);
  const float lg = log2f(gamma);
  const float cdk = exp2f(64.0f * lg);
  const int e0 = sl * 32;

  if (tid < 64) kdt[tid] = exp2f((float)(63 - tid) * lg);
  __syncthreads();

  f32x4 st[4];
#pragma unroll
  for (int t = 0; t < 4; ++t) st[t] = (f32x4){0.f, 0.f, 0.f, 0.f};

  for (int n = 0; n < 32; ++n) {
    const int row0 = b * 2048 + n * 64;
    const int t0 = n * 64;
#pragma unroll
    for (int t = 0; t < 4; ++t)
#pragma unroll
      for (int j = 0; j < 4; ++j)
        stb[(eb * 16 + hi * 4 + j) * LGK + (wr * 4 + t) * 16 + lr] = f2b(st[t][j]);
    u32x4 qf[8];
#pragma unroll
    for (int kk = 0; kk < 8; ++kk)
      qf[kk] = *(const u32x4*)&qk[(size_t)(row0 + wr * 16 + lr) * 4096 +
                                  hh * 256 + kk * 32 + hi * 8];
#pragma unroll
    for (int p = 0; p < 4; ++p) {
      int idx = p * 512 + tid;
      int c = idx >> 5, s = (idx & 31) * 8;
      *(uint4*)&ks[c * LGK + s] =
          *(const uint4*)&qk[(size_t)(row0 + c) * 4096 + 2048 + hh * 256 + s];
    }
#pragma unroll
    for (int p = 0; p < 4; ++p) {
      int idx = p * 512 + tid;
      int d = idx >> 3, cq = (idx & 7) * 8;
      union { uint4 v4; u16 h[8]; } pk;
      pk.v4 = *(const uint4*)&kt[((size_t)(b * 8 + hh) * 256 + d) * 2048 + t0 + cq];
      union { u16 h[8]; uint4 v4; } wo;
#pragma unroll
      for (int j2 = 0; j2 < 8; ++j2)
        wo.h[j2] = f2b(b2f(pk.h[j2]) * kdt[cq + j2]);
      *(uint4*)&ktd[d * LGC + cq] = wo.v4;
    }
#pragma unroll
    for (int p = 0; p < 4; ++p) {
      int c = (tid >> 5) + p * 16, e = tid & 31;
      vts[e * LGC + c] = v[(size_t)(row0 + c) * 4096 + hh * 512 + e0 + e];
    }
    __syncthreads();

    f32x4 att[2];
    att[0] = (f32x4){0.f, 0.f, 0.f, 0.f};
    att[1] = (f32x4){0.f, 0.f, 0.f, 0.f};
#pragma unroll
    for (int kk = 0; kk < 8; ++kk) {
#pragma unroll
      for (int jf = 0; jf < 2; ++jf) {
        u32x4 bb = *(const u32x4*)&ks[(eb * 32 + jf * 16 + lr) * LGK + kk * 32 + hi * 8];
        mfma_bf16(att[jf], qf[kk], bb);
      }
    }
#pragma unroll
    for (int jf = 0; jf < 2; ++jf)
#pragma unroll
      for (int j = 0; j < 4; ++j) {
        int i = wr * 16 + hi * 4 + j;
        int jc = eb * 32 + jf * 16 + lr;
        float mv = (i >= jc) ? exp2f((float)(i - jc) * lg) : 0.0f;
        ab[i * LGC + jc] = f2b(att[jf][j] * mv);
      }
    f32x4 occ = (f32x4){0.f, 0.f, 0.f, 0.f};
#pragma unroll
    for (int kk = 0; kk < 8; ++kk) {
      u32x4 bb = *(const u32x4*)&stb[(eb * 16 + lr) * LGK + kk * 32 + hi * 8];
      mfma_bf16(occ, qf[kk], bb);
    }
    __syncthreads();

#pragma unroll
    for (int j = 0; j < 4; ++j) {
      int i = wr * 16 + hi * 4 + j;
      occ[j] *= exp2f((float)(i + 1) * lg);
    }
#pragma unroll
    for (int kk = 0; kk < 2; ++kk) {
      u32x4 aa = *(const u32x4*)&ab[(wr * 16 + lr) * LGC + kk * 32 + hi * 8];
      u32x4 bb = *(const u32x4*)&vts[(eb * 16 + lr) * LGC + kk * 32 + hi * 8];
      mfma_bf16(occ, aa, bb);
    }
#pragma unroll
    for (int j = 0; j < 4; ++j) {
      int i = wr * 16 + hi * 4 + j;
      o[(size_t)(row0 + i) * 4096 + hh * 512 + e0 + eb * 16 + lr] = f2b(occ[j]);
    }
#pragma unroll
    for (int t = 0; t < 4; ++t) {
      st[t][0] *= cdk; st[t][1] *= cdk; st[t][2] *= cdk; st[t][3] *= cdk;
    }
#pragma unroll
    for (int kk = 0; kk < 2; ++kk) {
      u32x4 aa = *(const u32x4*)&vts[(eb * 16 + lr) * LGC + kk * 32 + hi * 8];
#pragma unroll
      for (int t = 0; t < 4; ++t) {
        u32x4 bb = *(const u32x4*)&ktd[((wr * 4 + t) * 16 + lr) * LGC + kk * 32 + hi * 8];
        mfma_bf16(st[t], aa, bb);
      }
    }
    __syncthreads();
  }
}

// =======================================================================
// Gated head-RMSNorm IN PLACE on o (bf16)
// =======================================================================
__global__ __launch_bounds__(64)
void gating_kernel(u16* __restrict__ o, const u16* __restrict__ g,
                   const float* __restrict__ gnw) {
  const int blk = blockIdx.x;
  const size_t base = (size_t)blk * 512;
  const int l = threadIdx.x;
  union { uint4 v4; u16 h[8]; } ov, gv;
  ov.v4 = *(const uint4*)&o[base + l * 8];
  float x[8];
  float ss = 0.f;
#pragma unroll
  for (int j = 0; j < 8; ++j) { x[j] = b2f(ov.h[j]); ss += x[j] * x[j]; }
#pragma unroll
  for (int m = 32; m; m >>= 1) ss += __shfl_xor(ss, m);
  const float sc = rsqrtf(ss * (1.0f / 512.0f) + 1e-6f);
  gv.v4 = *(const uint4*)&g[base + l * 8];
  union { u16 h[8]; uint4 v4; } ou;
#pragma unroll
  for (int j = 0; j < 8; ++j) {
    float gvf = b2f(gv.h[j]);
    float sig = 1.0f / (1.0f + expf(-gvf));
    ou.h[j] = f2b(x[j] * sc * gnw[l * 8 + j] * gvf * sig);
  }
  *(uint4*)&o[base + l * 8] = ou.v4;
}

// =======================================================================
extern "C" void kernel_launch(void* const* d_in, const int* in_sizes, int n_in,
                              void* d_out, int out_size, void* d_ws, size_t ws_size,
                              hipStream_t stream) {
  (void)in_sizes; (void)n_in; (void)out_size; (void)ws_size;
  const float* hidden      = (const float*)d_in[0];
  const float* attn_norm_w = (const float*)d_in[1];
  const float* q_w         = (const float*)d_in[2];
  const float* k_w         = (const float*)d_in[3];
  const float* v_w         = (const float*)d_in[4];
  const float* g_w         = (const float*)d_in[5];
  const float* o_w         = (const float*)d_in[6];
  const float* gnorm_w     = (const float*)d_in[7];
  const float* mlp_norm_w  = (const float*)d_in[8];
  const float* gate_w      = (const float*)d_in[9];
  const float* down_w      = (const float*)d_in[10];
  float* outp = (float*)d_out;

  char* ws = (char*)d_ws;
  size_t off = 0;
  auto alloc = [&](size_t bytes) -> char* {
    char* p = ws + off;
    off += (bytes + 255) & ~(size_t)255;
    return p;
  };
  u16*   W    = (u16*)alloc(23068672ULL);   // weight scratch (kt aliases)
  float* ctab = (float*)alloc(1048576ULL);
  float* stab = (float*)alloc(1048576ULL);
  u16*   hb   = (u16*)alloc(16777216ULL);
  u16*   qkb  = (u16*)alloc(33554432ULL);   // [4096][4096] = q|k combined
  u16*   vb   = (u16*)alloc(33554432ULL);
  u16*   gb   = (u16*)alloc(33554432ULL);
  u16*   ob   = (u16*)alloc(33554432ULL);
  u16*   resb = (u16*)alloc(16777216ULL);
  u16*   ybU  = qkb;   // [4096][5632] over qkb+vb (dead post-retention)
  u16*   kt   = W;     // [16][256][2048] while W idle (rope -> retention)

  rope_table_kernel<<<1024, 256, 0, stream>>>(ctab, stab);
  rmsnorm_cast_kernel<<<4096, 256, 0, stream>>>(hidden, attn_norm_w, hb);

  // QK combined projection: W = [qwT ; kwT], N=4096
  // gemm6 2D patches: nbm=32, nbn=32 -> pm=16, pn=8, gw=2; grid 1024
  transpose_cast_kernel<<<1024, 256, 0, stream>>>(q_w, W, 2048, 2048, 2048);
  transpose_cast_kernel<<<1024, 256, 0, stream>>>(k_w, W + 2048ULL * 2048, 2048, 2048, 2048);
  gemm6<1><<<1024, 256, 0, stream>>>(hb, W, (void*)qkb, nullptr, nullptr,
                                     4096, 2048, 2048, 16, 8, 2);
  // V projection
  transpose_cast_kernel<<<2048, 256, 0, stream>>>(v_w, W, 2048, 4096, 4096);
  gemm6<1><<<1024, 256, 0, stream>>>(hb, W, (void*)vb, nullptr, nullptr,
                                     4096, 2048, 2048, 16, 8, 2);
  // G projection
  transpose_cast_kernel<<<2048, 256, 0, stream>>>(g_w, W, 2048, 4096, 4096);
  gemm6<1><<<1024, 256, 0, stream>>>(hb, W, (void*)gb, nullptr, nullptr,
                                     4096, 2048, 2048, 16, 8, 2);

  // RoPE (+ q scale 1/16), then k -> kt
  rope_apply_kernel<<<4096, 256, 0, stream>>>(qkb, ctab, stab, 0, 0.0625f);
  rope_apply_kernel<<<4096, 256, 0, stream>>>(qkb, ctab, stab, 2048, 1.0f);
  transpose_k_kernel<<<2048, 256, 0, stream>>>(qkb, kt);

  // Retention scan -> ob
  retention_kernel<<<256, 512, 0, stream>>>(qkb, kt, vb, ob);

  // Gated head RMSNorm in place on ob
  gating_kernel<<<32768, 64, 0, stream>>>(ob, gb, gnorm_w);

  // O projection + residual(hidden) -> resb (nbm=32, nbn=16 -> 16,4,2)
  transpose_cast_kernel<<<2048, 256, 0, stream>>>(o_w, W, 4096, 2048, 2048);
  gemm6<4><<<512, 256, 0, stream>>>(ob, W, (void*)resb, hidden, nullptr,
                                    2048, 4096, 4096, 16, 4, 2);

  // MLP RMSNorm
  rmsnorm_bf16_kernel<<<4096, 256, 0, stream>>>(resb, mlp_norm_w, hb);

  // Up-half GEMM -> ybU (nbm=32, nbn=44 -> 16,11,2; grid 1408)
  transpose_cast_kernel<<<2816, 256, 0, stream>>>(gate_w + 5632, W, 2048, 5632, 11264);
  gemm6<1><<<1408, 256, 0, stream>>>(hb, W, (void*)ybU, nullptr, nullptr,
                                     5632, 2048, 2048, 16, 11, 2);
  // Gate-half GEMM fused SwiGLU in place over ybU
  transpose_cast_kernel<<<2816, 256, 0, stream>>>(gate_w, W, 2048, 5632, 11264);
  gemm6<3><<<1408, 256, 0, stream>>>(hb, W, (void*)ybU, nullptr, ybU,
                                     5632, 2048, 2048, 16, 11, 2);

  // Down projection + residual(resb) -> d_out (nbm=32, nbn=16 -> 16,4,2)
  transpose_cast_kernel<<<2816, 256, 0, stream>>>(down_w, W, 5632, 2048, 2048);
  gemm6<2><<<512, 256, 0, stream>>>(ybU, W, (void*)outp, nullptr, resb,
                                    2048, 5632, 5632, 16, 4, 2);
}

// Round 16
// 910.784 us; speedup vs baseline: 1.0522x; 1.0522x over previous
//
#include <hip/hip_runtime.h>
#include <cstdint>
#include <cstddef>

typedef unsigned short u16;
typedef __attribute__((ext_vector_type(4))) float f32x4;
typedef __attribute__((ext_vector_type(4))) unsigned int u32x4;
typedef __attribute__((ext_vector_type(8))) short s16x8;

// ---------- bf16 helpers (bit-level) ----------
__device__ __forceinline__ float b2f(u16 u) {
  union { unsigned int i; float f; } x; x.i = ((unsigned int)u) << 16; return x.f;
}
__device__ __forceinline__ u16 f2b(float f) {
  union { float f; unsigned int i; } x; x.f = f;
  unsigned int i = x.i;
  i += 0x7fffu + ((i >> 16) & 1u);   // RNE
  return (u16)(i >> 16);
}

// ---------- MFMA via compiler builtin (correct + native AGPR C/D) ----------
__device__ __forceinline__ void mfma_bf16(f32x4& c, u32x4 a, u32x4 b) {
  union { u32x4 u; s16x8 s; } ua, ub;
  ua.u = a; ub.u = b;
  c = __builtin_amdgcn_mfma_f32_16x16x32_bf16(ua.s, ub.s, c, 0, 0, 0);
}

// ---------- async global->LDS, 16B per lane ----------
__device__ __forceinline__ void async_ld16(const u16* g, u16* l) {
  typedef __attribute__((address_space(1))) const unsigned int GU;
  typedef __attribute__((address_space(3))) unsigned int LU;
  __builtin_amdgcn_global_load_lds((GU*)g, (LU*)l, 16, 0, 0);
}

// =======================================================================
// Weight transpose + cast: in[K][ldin] f32 (use N cols) -> out[N][K] bf16
// =======================================================================
__global__ __launch_bounds__(256)
void transpose_cast_kernel(const float* __restrict__ in, u16* __restrict__ out,
                           int K, int N, int ldin) {
  __shared__ float tile[64][65];
  const int nb = N >> 6;
  const int bk = blockIdx.x / nb, bn = blockIdx.x % nb;
  const int k0 = bk * 64, n0 = bn * 64;
  const int tid = threadIdx.x;
#pragma unroll
  for (int p = 0; p < 16; ++p) {
    int idx = p * 256 + tid;
    int r = idx >> 6, c = idx & 63;
    tile[r][c] = in[(size_t)(k0 + r) * ldin + n0 + c];
  }
  __syncthreads();
#pragma unroll
  for (int p = 0; p < 16; ++p) {
    int idx = p * 256 + tid;
    int r = idx >> 6, c = idx & 63;
    out[(size_t)(n0 + r) * K + k0 + c] = f2b(tile[c][r]);
  }
}

// =======================================================================
// k transpose from combined qk buffer -> kt [(b*8+h)*256+d][t]
// grid = 2048, block 256
// =======================================================================
__global__ __launch_bounds__(256)
void transpose_k_kernel(const u16* __restrict__ qk, u16* __restrict__ kt) {
  __shared__ u16 tile[64][72];
  const int bid = blockIdx.x;
  const int dd = bid & 3, tt = (bid >> 2) & 31;
  const int h = (bid >> 7) & 7, b = bid >> 10;
  const int t0 = tt * 64, d0 = dd * 64;
  const int tid = threadIdx.x;
#pragma unroll
  for (int p = 0; p < 2; ++p) {
    int idx = p * 256 + tid;
    int r = idx >> 3, cq = (idx & 7) * 8;
    *(uint4*)&tile[r][cq] =
        *(const uint4*)&qk[(size_t)(b * 2048 + t0 + r) * 4096 + 2048 + h * 256 + d0 + cq];
  }
  __syncthreads();
#pragma unroll
  for (int p = 0; p < 2; ++p) {
    int idx = p * 256 + tid;
    int r = idx >> 3, cq = (idx & 7) * 8;
    union { u16 h8[8]; uint4 v4; } o;
#pragma unroll
    for (int j = 0; j < 8; ++j) o.h8[j] = tile[cq + j][r];
    *(uint4*)&kt[((size_t)(b * 8 + h) * 256 + d0 + r) * 2048 + t0 + cq] = o.v4;
  }
}

// =======================================================================
// RMSNorm over 2048 f32 -> bf16
// =======================================================================
__global__ __launch_bounds__(256)
void rmsnorm_cast_kernel(const float* __restrict__ x, const float* __restrict__ w,
                         u16* __restrict__ out) {
  const int row = blockIdx.x, tid = threadIdx.x;
  const float* xr = x + (size_t)row * 2048;
  float4 a = ((const float4*)xr)[tid * 2];
  float4 b = ((const float4*)xr)[tid * 2 + 1];
  float ss = a.x*a.x + a.y*a.y + a.z*a.z + a.w*a.w
           + b.x*b.x + b.y*b.y + b.z*b.z + b.w*b.w;
#pragma unroll
  for (int m = 32; m; m >>= 1) ss += __shfl_xor(ss, m);
  __shared__ float ps[4];
  if ((tid & 63) == 0) ps[tid >> 6] = ss;
  __syncthreads();
  const float sc = rsqrtf((ps[0] + ps[1] + ps[2] + ps[3]) * (1.0f / 2048.0f) + 1e-6f);
  const int base = tid * 8;
  const float vals[8] = {a.x, a.y, a.z, a.w, b.x, b.y, b.z, b.w};
  union { u16 h[8]; uint4 v4[2]; } o;
#pragma unroll
  for (int j = 0; j < 8; ++j) o.h[j] = f2b(vals[j] * sc * w[base + j]);
  *(uint4*)&out[(size_t)row * 2048 + base] = o.v4[0];
  *(uint4*)&out[(size_t)row * 2048 + base + 8] = o.v4[1];
}

// =======================================================================
// RMSNorm over 2048 bf16 -> bf16
// =======================================================================
__global__ __launch_bounds__(256)
void rmsnorm_bf16_kernel(const u16* __restrict__ x, const float* __restrict__ w,
                         u16* __restrict__ out) {
  const int row = blockIdx.x, tid = threadIdx.x;
  union { uint4 v4; u16 h[8]; } p;
  p.v4 = *(const uint4*)&x[(size_t)row * 2048 + tid * 8];
  float v[8];
  float ss = 0.f;
#pragma unroll
  for (int j = 0; j < 8; ++j) { v[j] = b2f(p.h[j]); ss += v[j] * v[j]; }
#pragma unroll
  for (int m = 32; m; m >>= 1) ss += __shfl_xor(ss, m);
  __shared__ float ps[4];
  if ((tid & 63) == 0) ps[tid >> 6] = ss;
  __syncthreads();
  const float sc = rsqrtf((ps[0] + ps[1] + ps[2] + ps[3]) * (1.0f / 2048.0f) + 1e-6f);
  union { u16 h[8]; uint4 v4; } o;
#pragma unroll
  for (int j = 0; j < 8; ++j) o.h[j] = f2b(v[j] * sc * w[tid * 8 + j]);
  *(uint4*)&out[(size_t)row * 2048 + tid * 8] = o.v4;
}

// =======================================================================
// RoPE tables
// =======================================================================
__global__ __launch_bounds__(256)
void rope_table_kernel(float* __restrict__ ct, float* __restrict__ st) {
  const int idx = blockIdx.x * 256 + threadIdx.x;
  const int t = idx >> 7, i = idx & 127;
  const float e = -(float)i * (0.0078125f * log2f(10000.0f));
  const float ang = (float)t * exp2f(e);
  ct[idx] = cosf(ang);
  st[idx] = sinf(ang);
}

// =======================================================================
// RoPE apply in-place on combined qk buffer [4096][4096]
// =======================================================================
__global__ __launch_bounds__(256)
void rope_apply_kernel(u16* __restrict__ x, const float* __restrict__ ct,
                       const float* __restrict__ st, int qoff, float scale) {
  const int gid = blockIdx.x * 256 + threadIdx.x;
  const int r = gid >> 8;
  const int rem = gid & 255;
  const int h = rem >> 5;
  const int i4 = (rem & 31) * 4;
  const int t = r & 2047;
  const size_t o1 = (size_t)r * 4096 + qoff + h * 256 + i4;
  union { ushort4 v; u16 h4[4]; } p1, p2, q1, q2;
  p1.v = *(ushort4*)&x[o1];
  p2.v = *(ushort4*)&x[o1 + 128];
  const float4 c = *(const float4*)&ct[t * 128 + i4];
  const float4 s = *(const float4*)&st[t * 128 + i4];
  const float cc[4] = {c.x, c.y, c.z, c.w};
  const float sn[4] = {s.x, s.y, s.z, s.w};
#pragma unroll
  for (int j = 0; j < 4; ++j) {
    float x1 = b2f(p1.h4[j]), x2 = b2f(p2.h4[j]);
    q1.h4[j] = f2b((x1 * cc[j] - x2 * sn[j]) * scale);
    q2.h4[j] = f2b((x2 * cc[j] + x1 * sn[j]) * scale);
  }
  *(ushort4*)&x[o1] = q1.v;
  *(ushort4*)&x[o1 + 128] = q2.v;
}

// =======================================================================
// GEMM v4 (r8's proven 4-phase deep pipeline, BM=256 for N=4096 projs).
// =======================================================================
template <int BM, int EPI>
__global__ __launch_bounds__(512, 2)
void gemm4(const u16* __restrict__ A, const u16* __restrict__ Bt,
           void* Cout, const float* fsrc, const u16* hsrc,
           int N, int K, int lda, int pm, int pn, int gw) {
  constexpr int MF = BM / 32;
  constexpr int LA = BM / 128;
  constexpr int AH = BM * 64;
  constexpr int BH = 16384;
  constexpr int BUFB = 2 * AH + 2 * BH;
  constexpr int VMC = (BM == 256) ? 8 : 6;
  __shared__ __align__(16) char smem[2 * BUFB];

  const int tid = threadIdx.x;
  const int l = tid & 63, w = tid >> 6;
  const int lr = l & 15, hi = l >> 4;
  const int wm = w >> 2, wn = w & 3;
  const int xcd = blockIdx.x & 7;
  const int jj = blockIdx.x >> 3;
  const int gx = xcd % gw, gy = xcd / gw;
  const int bm = gx * pm + jj / pn;
  const int bn = gy * pn + jj % pn;
  const int nt = K >> 6;

  const int rA = tid >> 2;
  const int chx = (tid & 3) ^ ((tid >> 3) & 3);
  const u16* Ag = A + (size_t)(bm * BM + rA) * lda + chx * 8;
  const u16* Bg = Bt + (size_t)(bn * 256 + rA) * K + chx * 8;
  const int wb = w * 1024;

  int aoff[MF], boff[4];
#pragma unroll
  for (int mf = 0; mf < MF; ++mf) {
    int r = wm * (BM / 2) + mf * 16 + lr;
    aoff[mf] = (r * 4 + (hi ^ ((r >> 1) & 3))) * 16;
  }
#pragma unroll
  for (int nf = 0; nf < 4; ++nf) {
    int r = wn * 64 + nf * 16 + lr;
    boff[nf] = (r * 4 + (hi ^ ((r >> 1) & 3))) * 16;
  }

  f32x4 acc[MF][4];
#pragma unroll
  for (int m = 0; m < MF; ++m)
#pragma unroll
    for (int n = 0; n < 4; ++n) acc[m][n] = (f32x4){0.f, 0.f, 0.f, 0.f};
  u32x4 af[4], bf[4];

#define STA(kt, ks, bb)                                                        \
  { _Pragma("unroll") for (int t = 0; t < LA; ++t)                             \
      async_ld16(Ag + (size_t)t * 128 * lda + (kt) * 64 + (ks) * 32,           \
                 (u16*)(smem + (bb) * BUFB + (ks) * AH + t * 8192 + wb)); }
#define STB(kt, ks, bb)                                                        \
  { _Pragma("unroll") for (int t = 0; t < 2; ++t)                              \
      async_ld16(Bg + (size_t)t * 128 * K + (kt) * 64 + (ks) * 32,             \
                 (u16*)(smem + (bb) * BUFB + 2 * AH + (ks) * BH + t * 8192 + wb)); }
#define RDA(mh, ks, bb)                                                        \
  { _Pragma("unroll") for (int mf = 0; mf < 4; ++mf)                           \
      af[mf] = *(const u32x4*)(smem + (bb) * BUFB + (ks) * AH + aoff[(mh) * 4 + mf]); }
#define RDB(ks, bb)                                                            \
  { _Pragma("unroll") for (int nf = 0; nf < 4; ++nf)                           \
      bf[nf] = *(const u32x4*)(smem + (bb) * BUFB + 2 * AH + (ks) * BH + boff[nf]); }
#define MM(mh)                                                                 \
  { _Pragma("unroll") for (int mf = 0; mf < 4; ++mf)                           \
      _Pragma("unroll") for (int nf = 0; nf < 4; ++nf)                         \
        mfma_bf16(acc[(mh) * 4 + mf][nf], af[mf], bf[nf]); }
#define SB   __builtin_amdgcn_sched_barrier(0)
#define BARR __builtin_amdgcn_s_barrier()
#define VMW  asm volatile("s_waitcnt vmcnt(%0)" :: "n"(VMC) : "memory")

  STA(0, 0, 0); STB(0, 0, 0); STA(0, 1, 0); STB(0, 1, 0);
  STA(1, 0, 1); STB(1, 0, 1);
  SB; VMW; SB; BARR; SB;

  for (int i = 0; i < nt; ++i) {
    const int bb = i & 1, ob = bb ^ 1;
    const int t1 = (i + 1 < nt) ? i + 1 : 0;
    const int t2 = (i + 2 < nt) ? i + 2 : 0;
    RDA(0, 0, bb); RDB(0, bb);
    STA(t1, 1, ob);
    SB; BARR;
    __builtin_amdgcn_s_setprio(1); MM(0); __builtin_amdgcn_s_setprio(0);
    SB; BARR; SB;
    RDA(1, 0, bb);
    STB(t1, 1, ob);
    SB; BARR;
    __builtin_amdgcn_s_setprio(1); MM(1); __builtin_amdgcn_s_setprio(0);
    SB; VMW; BARR; SB;
    RDA(0, 1, bb); RDB(1, bb);
    STA(t2, 0, bb);
    SB; BARR;
    __builtin_amdgcn_s_setprio(1); MM(0); __builtin_amdgcn_s_setprio(0);
    SB; BARR; SB;
    RDA(1, 1, bb);
    STB(t2, 0, bb);
    SB; BARR;
    __builtin_amdgcn_s_setprio(1); MM(1); __builtin_amdgcn_s_setprio(0);
    SB; VMW; BARR; SB;
  }
#undef STA
#undef STB
#undef RDA
#undef RDB
#undef MM
#undef SB
#undef BARR
#undef VMW

  const size_t crow0 = (size_t)(bm * BM + wm * (BM / 2));
  const int ccol0 = bn * 256 + wn * 64;
#pragma unroll
  for (int m = 0; m < MF; ++m)
#pragma unroll
    for (int n = 0; n < 4; ++n)
#pragma unroll
      for (int j2 = 0; j2 < 4; ++j2) {
        size_t r = crow0 + m * 16 + hi * 4 + j2;
        size_t c = (size_t)(ccol0 + n * 16 + lr);
        size_t idx = r * N + c;
        float a = acc[m][n][j2];
        (void)fsrc; (void)hsrc;
        ((u16*)Cout)[idx] = f2b(a);
      }
}

// =======================================================================
// GEMM v6 (r10's proven dbuf + counted-vmcnt, 128x128, 4 blocks/CU,
// 2D XCD patches).  grid = 8*pm*pn, gw*pm == nbm, (8/gw)*pn == nbn.
// EPI: 1 bf16; 2 f32 acc+b2f(hsrc); 3 bf16 silu(acc)*b2f(hsrc); 4 bf16 acc+fsrc
// =======================================================================
template <int EPI>
__global__ __launch_bounds__(256, 4)
void gemm6(const u16* __restrict__ A, const u16* __restrict__ Bt,
           void* Cout, const float* fsrc, const u16* hsrc,
           int N, int K, int lda, int pm, int pn, int gw) {
  __shared__ __align__(16) char smem[2][16384];   // per buf: A 8KB | B 8KB
  const int tid = threadIdx.x;
  const int l = tid & 63, w = tid >> 6;
  const int lr = l & 15, hi = l >> 4;
  const int wm = w >> 1, wn = w & 1;
  const int xcd = blockIdx.x & 7;
  const int jj = blockIdx.x >> 3;
  const int gx = xcd % gw, gy = xcd / gw;
  const int bm = gx * pm + jj / pn;
  const int bn = gy * pn + jj % pn;
  const int nt = K >> 5;

  const u16* Ap[2]; const u16* Bp[2];
#pragma unroll
  for (int t = 0; t < 2; ++t) {
    int s = t * 256 + tid;
    int row = s >> 2, ch = (s & 3) ^ ((s >> 3) & 3);
    Ap[t] = A + (size_t)(bm * 128 + row) * lda + ch * 8;
    Bp[t] = Bt + (size_t)(bn * 128 + row) * K + ch * 8;
  }
  const int dst0 = (0 * 256 + w * 64) * 16;
  const int dst1 = (1 * 256 + w * 64) * 16;

  int aoff[4], boff[4];
#pragma unroll
  for (int f = 0; f < 4; ++f) {
    int ra = wm * 64 + f * 16 + lr;
    aoff[f] = (ra * 4 + (hi ^ ((ra >> 1) & 3))) * 16;
    int rb = wn * 64 + f * 16 + lr;
    boff[f] = 8192 + (rb * 4 + (hi ^ ((rb >> 1) & 3))) * 16;
  }

  f32x4 acc[4][4];
#pragma unroll
  for (int m = 0; m < 4; ++m)
#pragma unroll
    for (int n = 0; n < 4; ++n) acc[m][n] = (f32x4){0.f, 0.f, 0.f, 0.f};

#define SB __builtin_amdgcn_sched_barrier(0)
  auto stage = [&](int i, int s) {
    const int k0 = i * 32;
    async_ld16(Ap[0] + k0, (u16*)(smem[s] + dst0));
    async_ld16(Ap[1] + k0, (u16*)(smem[s] + dst1));
    async_ld16(Bp[0] + k0, (u16*)(smem[s] + 8192 + dst0));
    async_ld16(Bp[1] + k0, (u16*)(smem[s] + 8192 + dst1));
  };

  stage(0, 0);
  SB;
  for (int i = 0; i < nt; ++i) {
    const int cur = i & 1;
    const int ip = (i + 1 < nt) ? i + 1 : 0;     // tail: dead re-stage
    stage(ip, cur ^ 1);
    SB;
    asm volatile("s_waitcnt vmcnt(4)" ::: "memory");   // tile i landed
    SB;
    __builtin_amdgcn_s_barrier();
    SB;
    u32x4 af[4], bf[4];
#pragma unroll
    for (int f = 0; f < 4; ++f) af[f] = *(const u32x4*)(smem[cur] + aoff[f]);
#pragma unroll
    for (int f = 0; f < 4; ++f) bf[f] = *(const u32x4*)(smem[cur] + boff[f]);
    __builtin_amdgcn_s_setprio(1);
#pragma unroll
    for (int m = 0; m < 4; ++m)
#pragma unroll
      for (int n = 0; n < 4; ++n) mfma_bf16(acc[m][n], af[m], bf[n]);
    __builtin_amdgcn_s_setprio(0);
    SB;
    __builtin_amdgcn_s_barrier();    // raw: no vmcnt drain
    SB;
  }
#undef SB

  const size_t crow0 = (size_t)(bm * 128 + wm * 64);
  const int ccol0 = bn * 128 + wn * 64;
#pragma unroll
  for (int m = 0; m < 4; ++m)
#pragma unroll
    for (int n = 0; n < 4; ++n)
#pragma unroll
      for (int j2 = 0; j2 < 4; ++j2) {
        size_t r = crow0 + m * 16 + hi * 4 + j2;
        size_t c = (size_t)(ccol0 + n * 16 + lr);
        size_t idx = r * N + c;
        float a = acc[m][n][j2];
        if (EPI == 1) {
          ((u16*)Cout)[idx] = f2b(a);
        } else if (EPI == 2) {
          ((float*)Cout)[idx] = a + b2f(hsrc[idx]);
        } else if (EPI == 3) {
          float u = b2f(hsrc[idx]);
          ((u16*)Cout)[idx] = f2b(a / (1.0f + expf(-a)) * u);
        } else {
          ((u16*)Cout)[idx] = f2b(a + fsrc[idx]);
        }
      }
}

// =======================================================================
// Chunkwise retention scan (unchanged).
// =======================================================================
#define LGK 264
#define LGC 72
__global__ __launch_bounds__(512)
void retention_kernel(const u16* __restrict__ qk, const u16* __restrict__ kt,
                      const u16* __restrict__ v, u16* __restrict__ o) {
  __shared__ __align__(16) u16 ks[64 * LGK];
  __shared__ __align__(16) u16 stb[32 * LGK];
  __shared__ __align__(16) u16 ktd[256 * LGC];
  __shared__ __align__(16) u16 vts[32 * LGC];
  __shared__ __align__(16) u16 ab[64 * LGC];
  __shared__ float kdt[64];

  const int tid = threadIdx.x;
  const int l = tid & 63, w = tid >> 6;
  const int lr = l & 15, hi = l >> 4;
  const int wr = w >> 1;
  const int eb = w & 1;
  const int bid = blockIdx.x;
  const int g = bid & 15;
  const int sl = bid >> 4;
  const int hh = g & 7;
  const int b = g >> 3;
  const float gamma = 1.0f - exp2f(-5.0f - (float)hh);
  const float lg = log2f(gamma);
  const float cdk = exp2f(64.0f * lg);
  const int e0 = sl * 32;

  if (tid < 64) kdt[tid] = exp2f((float)(63 - tid) * lg);
  __syncthreads();

  f32x4 st[4];
#pragma unroll
  for (int t = 0; t < 4; ++t) st[t] = (f32x4){0.f, 0.f, 0.f, 0.f};

  for (int n = 0; n < 32; ++n) {
    const int row0 = b * 2048 + n * 64;
    const int t0 = n * 64;
#pragma unroll
    for (int t = 0; t < 4; ++t)
#pragma unroll
      for (int j = 0; j < 4; ++j)
        stb[(eb * 16 + hi * 4 + j) * LGK + (wr * 4 + t) * 16 + lr] = f2b(st[t][j]);
    u32x4 qf[8];
#pragma unroll
    for (int kk = 0; kk < 8; ++kk)
      qf[kk] = *(const u32x4*)&qk[(size_t)(row0 + wr * 16 + lr) * 4096 +
                                  hh * 256 + kk * 32 + hi * 8];
#pragma unroll
    for (int p = 0; p < 4; ++p) {
      int idx = p * 512 + tid;
      int c = idx >> 5, s = (idx & 31) * 8;
      *(uint4*)&ks[c * LGK + s] =
          *(const uint4*)&qk[(size_t)(row0 + c) * 4096 + 2048 + hh * 256 + s];
    }
#pragma unroll
    for (int p = 0; p < 4; ++p) {
      int idx = p * 512 + tid;
      int d = idx >> 3, cq = (idx & 7) * 8;
      union { uint4 v4; u16 h[8]; } pk;
      pk.v4 = *(const uint4*)&kt[((size_t)(b * 8 + hh) * 256 + d) * 2048 + t0 + cq];
      union { u16 h[8]; uint4 v4; } wo;
#pragma unroll
      for (int j2 = 0; j2 < 8; ++j2)
        wo.h[j2] = f2b(b2f(pk.h[j2]) * kdt[cq + j2]);
      *(uint4*)&ktd[d * LGC + cq] = wo.v4;
    }
#pragma unroll
    for (int p = 0; p < 4; ++p) {
      int c = (tid >> 5) + p * 16, e = tid & 31;
      vts[e * LGC + c] = v[(size_t)(row0 + c) * 4096 + hh * 512 + e0 + e];
    }
    __syncthreads();

    f32x4 att[2];
    att[0] = (f32x4){0.f, 0.f, 0.f, 0.f};
    att[1] = (f32x4){0.f, 0.f, 0.f, 0.f};
#pragma unroll
    for (int kk = 0; kk < 8; ++kk) {
#pragma unroll
      for (int jf = 0; jf < 2; ++jf) {
        u32x4 bb = *(const u32x4*)&ks[(eb * 32 + jf * 16 + lr) * LGK + kk * 32 + hi * 8];
        mfma_bf16(att[jf], qf[kk], bb);
      }
    }
#pragma unroll
    for (int jf = 0; jf < 2; ++jf)
#pragma unroll
      for (int j = 0; j < 4; ++j) {
        int i = wr * 16 + hi * 4 + j;
        int jc = eb * 32 + jf * 16 + lr;
        float mv = (i >= jc) ? exp2f((float)(i - jc) * lg) : 0.0f;
        ab[i * LGC + jc] = f2b(att[jf][j] * mv);
      }
    f32x4 occ = (f32x4){0.f, 0.f, 0.f, 0.f};
#pragma unroll
    for (int kk = 0; kk < 8; ++kk) {
      u32x4 bb = *(const u32x4*)&stb[(eb * 16 + lr) * LGK + kk * 32 + hi * 8];
      mfma_bf16(occ, qf[kk], bb);
    }
    __syncthreads();

#pragma unroll
    for (int j = 0; j < 4; ++j) {
      int i = wr * 16 + hi * 4 + j;
      occ[j] *= exp2f((float)(i + 1) * lg);
    }
#pragma unroll
    for (int kk = 0; kk < 2; ++kk) {
      u32x4 aa = *(const u32x4*)&ab[(wr * 16 + lr) * LGC + kk * 32 + hi * 8];
      u32x4 bb = *(const u32x4*)&vts[(eb * 16 + lr) * LGC + kk * 32 + hi * 8];
      mfma_bf16(occ, aa, bb);
    }
#pragma unroll
    for (int j = 0; j < 4; ++j) {
      int i = wr * 16 + hi * 4 + j;
      o[(size_t)(row0 + i) * 4096 + hh * 512 + e0 + eb * 16 + lr] = f2b(occ[j]);
    }
#pragma unroll
    for (int t = 0; t < 4; ++t) {
      st[t][0] *= cdk; st[t][1] *= cdk; st[t][2] *= cdk; st[t][3] *= cdk;
    }
#pragma unroll
    for (int kk = 0; kk < 2; ++kk) {
      u32x4 aa = *(const u32x4*)&vts[(eb * 16 + lr) * LGC + kk * 32 + hi * 8];
#pragma unroll
      for (int t = 0; t < 4; ++t) {
        u32x4 bb = *(const u32x4*)&ktd[((wr * 4 + t) * 16 + lr) * LGC + kk * 32 + hi * 8];
        mfma_bf16(st[t], aa, bb);
      }
    }
    __syncthreads();
  }
}

// =======================================================================
// Gated head-RMSNorm IN PLACE on o (bf16)
// =======================================================================
__global__ __launch_bounds__(64)
void gating_kernel(u16* __restrict__ o, const u16* __restrict__ g,
                   const float* __restrict__ gnw) {
  const int blk = blockIdx.x;
  const size_t base = (size_t)blk * 512;
  const int l = threadIdx.x;
  union { uint4 v4; u16 h[8]; } ov, gv;
  ov.v4 = *(const uint4*)&o[base + l * 8];
  float x[8];
  float ss = 0.f;
#pragma unroll
  for (int j = 0; j < 8; ++j) { x[j] = b2f(ov.h[j]); ss += x[j] * x[j]; }
#pragma unroll
  for (int m = 32; m; m >>= 1) ss += __shfl_xor(ss, m);
  const float sc = rsqrtf(ss * (1.0f / 512.0f) + 1e-6f);
  gv.v4 = *(const uint4*)&g[base + l * 8];
  union { u16 h[8]; uint4 v4; } ou;
#pragma unroll
  for (int j = 0; j < 8; ++j) {
    float gvf = b2f(gv.h[j]);
    float sig = 1.0f / (1.0f + expf(-gvf));
    ou.h[j] = f2b(x[j] * sc * gnw[l * 8 + j] * gvf * sig);
  }
  *(uint4*)&o[base + l * 8] = ou.v4;
}

// =======================================================================
extern "C" void kernel_launch(void* const* d_in, const int* in_sizes, int n_in,
                              void* d_out, int out_size, void* d_ws, size_t ws_size,
                              hipStream_t stream) {
  (void)in_sizes; (void)n_in; (void)out_size; (void)ws_size;
  const float* hidden      = (const float*)d_in[0];
  const float* attn_norm_w = (const float*)d_in[1];
  const float* q_w         = (const float*)d_in[2];
  const float* k_w         = (const float*)d_in[3];
  const float* v_w         = (const float*)d_in[4];
  const float* g_w         = (const float*)d_in[5];
  const float* o_w         = (const float*)d_in[6];
  const float* gnorm_w     = (const float*)d_in[7];
  const float* mlp_norm_w  = (const float*)d_in[8];
  const float* gate_w      = (const float*)d_in[9];
  const float* down_w      = (const float*)d_in[10];
  float* outp = (float*)d_out;

  char* ws = (char*)d_ws;
  size_t off = 0;
  auto alloc = [&](size_t bytes) -> char* {
    char* p = ws + off;
    off += (bytes + 255) & ~(size_t)255;
    return p;
  };
  u16*   W    = (u16*)alloc(23068672ULL);   // weight scratch (kt aliases)
  float* ctab = (float*)alloc(1048576ULL);
  float* stab = (float*)alloc(1048576ULL);
  u16*   hb   = (u16*)alloc(16777216ULL);
  u16*   qkb  = (u16*)alloc(33554432ULL);   // [4096][4096] = q|k combined
  u16*   vb   = (u16*)alloc(33554432ULL);
  u16*   gb   = (u16*)alloc(33554432ULL);
  u16*   ob   = (u16*)alloc(33554432ULL);
  u16*   resb = (u16*)alloc(16777216ULL);
  u16*   ybU  = qkb;   // [4096][5632] over qkb+vb (dead post-retention)
  u16*   kt   = W;     // [16][256][2048] while W idle (rope -> retention)

  rope_table_kernel<<<1024, 256, 0, stream>>>(ctab, stab);
  rmsnorm_cast_kernel<<<4096, 256, 0, stream>>>(hidden, attn_norm_w, hb);

  // QK combined projection: W = [qwT ; kwT], N=4096 (gemm4-256, grid 256)
  transpose_cast_kernel<<<1024, 256, 0, stream>>>(q_w, W, 2048, 2048, 2048);
  transpose_cast_kernel<<<1024, 256, 0, stream>>>(k_w, W + 2048ULL * 2048, 2048, 2048, 2048);
  gemm4<256, 1><<<256, 512, 0, stream>>>(hb, W, (void*)qkb, nullptr, nullptr,
                                         4096, 2048, 2048, 8, 4, 2);
  // V projection
  transpose_cast_kernel<<<2048, 256, 0, stream>>>(v_w, W, 2048, 4096, 4096);
  gemm4<256, 1><<<256, 512, 0, stream>>>(hb, W, (void*)vb, nullptr, nullptr,
                                         4096, 2048, 2048, 8, 4, 2);
  // G projection
  transpose_cast_kernel<<<2048, 256, 0, stream>>>(g_w, W, 2048, 4096, 4096);
  gemm4<256, 1><<<256, 512, 0, stream>>>(hb, W, (void*)gb, nullptr, nullptr,
                                         4096, 2048, 2048, 8, 4, 2);

  // RoPE (+ q scale 1/16), then k -> kt
  rope_apply_kernel<<<4096, 256, 0, stream>>>(qkb, ctab, stab, 0, 0.0625f);
  rope_apply_kernel<<<4096, 256, 0, stream>>>(qkb, ctab, stab, 2048, 1.0f);
  transpose_k_kernel<<<2048, 256, 0, stream>>>(qkb, kt);

  // Retention scan -> ob
  retention_kernel<<<256, 512, 0, stream>>>(qkb, kt, vb, ob);

  // Gated head RMSNorm in place on ob
  gating_kernel<<<32768, 64, 0, stream>>>(ob, gb, gnorm_w);

  // O projection + residual(hidden) -> resb (gemm6 2D patches: nbm=32,
  // nbn=16 -> pm=16, pn=4, gw=2; grid 512)
  transpose_cast_kernel<<<2048, 256, 0, stream>>>(o_w, W, 4096, 2048, 2048);
  gemm6<4><<<512, 256, 0, stream>>>(ob, W, (void*)resb, hidden, nullptr,
                                    2048, 4096, 4096, 16, 4, 2);

  // MLP RMSNorm
  rmsnorm_bf16_kernel<<<4096, 256, 0, stream>>>(resb, mlp_norm_w, hb);

  // Up-half GEMM -> ybU (gemm6: nbm=32, nbn=44 -> pm=16, pn=11, gw=2;
  // grid 1408)
  transpose_cast_kernel<<<2816, 256, 0, stream>>>(gate_w + 5632, W, 2048, 5632, 11264);
  gemm6<1><<<1408, 256, 0, stream>>>(hb, W, (void*)ybU, nullptr, nullptr,
                                     5632, 2048, 2048, 16, 11, 2);
  // Gate-half GEMM fused SwiGLU in place over ybU
  transpose_cast_kernel<<<2816, 256, 0, stream>>>(gate_w, W, 2048, 5632, 11264);
  gemm6<3><<<1408, 256, 0, stream>>>(hb, W, (void*)ybU, nullptr, ybU,
                                     5632, 2048, 2048, 16, 11, 2);

  // Down projection + residual(resb) -> d_out (gemm6: nbm=32, nbn=16 ->
  // pm=16, pn=4, gw=2; grid 512)
  transpose_cast_kernel<<<2816, 256, 0, stream>>>(down_w, W, 5632, 2048, 2048);
  gemm6<2><<<512, 256, 0, stream>>>(ybU, W, (void*)outp, nullptr, resb,
                                    2048, 5632, 5632, 16, 4, 2);
}

// Round 17
// 906.363 us; speedup vs baseline: 1.0573x; 1.0049x over previous
//
#include <hip/hip_runtime.h>
#include <cstdint>
#include <cstddef>

typedef unsigned short u16;
typedef __attribute__((ext_vector_type(4))) float f32x4;
typedef __attribute__((ext_vector_type(4))) unsigned int u32x4;
typedef __attribute__((ext_vector_type(8))) short s16x8;

// ---------- bf16 helpers (bit-level) ----------
__device__ __forceinline__ float b2f(u16 u) {
  union { unsigned int i; float f; } x; x.i = ((unsigned int)u) << 16; return x.f;
}
__device__ __forceinline__ u16 f2b(float f) {
  union { float f; unsigned int i; } x; x.f = f;
  unsigned int i = x.i;
  i += 0x7fffu + ((i >> 16) & 1u);   // RNE
  return (u16)(i >> 16);
}

// ---------- MFMA via compiler builtin (correct + native AGPR C/D) ----------
__device__ __forceinline__ void mfma_bf16(f32x4& c, u32x4 a, u32x4 b) {
  union { u32x4 u; s16x8 s; } ua, ub;
  ua.u = a; ub.u = b;
  c = __builtin_amdgcn_mfma_f32_16x16x32_bf16(ua.s, ub.s, c, 0, 0, 0);
}

// ---------- async global->LDS, 16B per lane ----------
__device__ __forceinline__ void async_ld16(const u16* g, u16* l) {
  typedef __attribute__((address_space(1))) const unsigned int GU;
  typedef __attribute__((address_space(3))) unsigned int LU;
  __builtin_amdgcn_global_load_lds((GU*)g, (LU*)l, 16, 0, 0);
}

// =======================================================================
// Weight transpose + cast: in[K][ldin] f32 (use N cols) -> out[N][K] bf16
// ROUND 17: vectorized (G13).  Read: float4 = 16B/lane.  Write: uint4
// (8 bf16) = 16B/lane, coalesced & aligned (k0%64==0, c0%8==0).  Old
// version wrote 2B/lane -- the dominant cost of the 7 transpose passes
// (~400 MB total).  LDS pad 65: read stride 8*65 mod 32 = 8 -> 2-way
// bank aliasing (free, m136).
// =======================================================================
__global__ __launch_bounds__(256)
void transpose_cast_kernel(const float* __restrict__ in, u16* __restrict__ out,
                           int K, int N, int ldin) {
  __shared__ float tile[64][65];
  const int nb = N >> 6;
  const int bk = blockIdx.x / nb, bn = blockIdx.x % nb;
  const int k0 = bk * 64, n0 = bn * 64;
  const int tid = threadIdx.x;
#pragma unroll
  for (int p = 0; p < 4; ++p) {
    int vi = p * 256 + tid;
    int r = vi >> 4, c4 = (vi & 15) * 4;
    float4 v = *(const float4*)&in[(size_t)(k0 + r) * ldin + n0 + c4];
    tile[r][c4]     = v.x;
    tile[r][c4 + 1] = v.y;
    tile[r][c4 + 2] = v.z;
    tile[r][c4 + 3] = v.w;
  }
  __syncthreads();
#pragma unroll
  for (int p = 0; p < 2; ++p) {
    int fi = p * 256 + tid;
    int r = fi >> 3, c0 = (fi & 7) * 8;
    union { u16 h[8]; uint4 v4; } o;
#pragma unroll
    for (int j = 0; j < 8; ++j) o.h[j] = f2b(tile[c0 + j][r]);
    *(uint4*)&out[(size_t)(n0 + r) * K + k0 + c0] = o.v4;
  }
}

// =======================================================================
// k transpose from combined qk buffer -> kt [(b*8+h)*256+d][t]
// grid = 2048, block 256
// =======================================================================
__global__ __launch_bounds__(256)
void transpose_k_kernel(const u16* __restrict__ qk, u16* __restrict__ kt) {
  __shared__ u16 tile[64][72];
  const int bid = blockIdx.x;
  const int dd = bid & 3, tt = (bid >> 2) & 31;
  const int h = (bid >> 7) & 7, b = bid >> 10;
  const int t0 = tt * 64, d0 = dd * 64;
  const int tid = threadIdx.x;
#pragma unroll
  for (int p = 0; p < 2; ++p) {
    int idx = p * 256 + tid;
    int r = idx >> 3, cq = (idx & 7) * 8;
    *(uint4*)&tile[r][cq] =
        *(const uint4*)&qk[(size_t)(b * 2048 + t0 + r) * 4096 + 2048 + h * 256 + d0 + cq];
  }
  __syncthreads();
#pragma unroll
  for (int p = 0; p < 2; ++p) {
    int idx = p * 256 + tid;
    int r = idx >> 3, cq = (idx & 7) * 8;
    union { u16 h8[8]; uint4 v4; } o;
#pragma unroll
    for (int j = 0; j < 8; ++j) o.h8[j] = tile[cq + j][r];
    *(uint4*)&kt[((size_t)(b * 8 + h) * 256 + d0 + r) * 2048 + t0 + cq] = o.v4;
  }
}

// =======================================================================
// RMSNorm over 2048 f32 -> bf16
// =======================================================================
__global__ __launch_bounds__(256)
void rmsnorm_cast_kernel(const float* __restrict__ x, const float* __restrict__ w,
                         u16* __restrict__ out) {
  const int row = blockIdx.x, tid = threadIdx.x;
  const float* xr = x + (size_t)row * 2048;
  float4 a = ((const float4*)xr)[tid * 2];
  float4 b = ((const float4*)xr)[tid * 2 + 1];
  float ss = a.x*a.x + a.y*a.y + a.z*a.z + a.w*a.w
           + b.x*b.x + b.y*b.y + b.z*b.z + b.w*b.w;
#pragma unroll
  for (int m = 32; m; m >>= 1) ss += __shfl_xor(ss, m);
  __shared__ float ps[4];
  if ((tid & 63) == 0) ps[tid >> 6] = ss;
  __syncthreads();
  const float sc = rsqrtf((ps[0] + ps[1] + ps[2] + ps[3]) * (1.0f / 2048.0f) + 1e-6f);
  const int base = tid * 8;
  const float vals[8] = {a.x, a.y, a.z, a.w, b.x, b.y, b.z, b.w};
  union { u16 h[8]; uint4 v4[2]; } o;
#pragma unroll
  for (int j = 0; j < 8; ++j) o.h[j] = f2b(vals[j] * sc * w[base + j]);
  *(uint4*)&out[(size_t)row * 2048 + base] = o.v4[0];
  *(uint4*)&out[(size_t)row * 2048 + base + 8] = o.v4[1];
}

// =======================================================================
// RMSNorm over 2048 bf16 -> bf16
// =======================================================================
__global__ __launch_bounds__(256)
void rmsnorm_bf16_kernel(const u16* __restrict__ x, const float* __restrict__ w,
                         u16* __restrict__ out) {
  const int row = blockIdx.x, tid = threadIdx.x;
  union { uint4 v4; u16 h[8]; } p;
  p.v4 = *(const uint4*)&x[(size_t)row * 2048 + tid * 8];
  float v[8];
  float ss = 0.f;
#pragma unroll
  for (int j = 0; j < 8; ++j) { v[j] = b2f(p.h[j]); ss += v[j] * v[j]; }
#pragma unroll
  for (int m = 32; m; m >>= 1) ss += __shfl_xor(ss, m);
  __shared__ float ps[4];
  if ((tid & 63) == 0) ps[tid >> 6] = ss;
  __syncthreads();
  const float sc = rsqrtf((ps[0] + ps[1] + ps[2] + ps[3]) * (1.0f / 2048.0f) + 1e-6f);
  union { u16 h[8]; uint4 v4; } o;
#pragma unroll
  for (int j = 0; j < 8; ++j) o.h[j] = f2b(v[j] * sc * w[tid * 8 + j]);
  *(uint4*)&out[(size_t)row * 2048 + tid * 8] = o.v4;
}

// =======================================================================
// RoPE tables
// =======================================================================
__global__ __launch_bounds__(256)
void rope_table_kernel(float* __restrict__ ct, float* __restrict__ st) {
  const int idx = blockIdx.x * 256 + threadIdx.x;
  const int t = idx >> 7, i = idx & 127;
  const float e = -(float)i * (0.0078125f * log2f(10000.0f));
  const float ang = (float)t * exp2f(e);
  ct[idx] = cosf(ang);
  st[idx] = sinf(ang);
}

// =======================================================================
// RoPE apply in-place on combined qk buffer [4096][4096]
// =======================================================================
__global__ __launch_bounds__(256)
void rope_apply_kernel(u16* __restrict__ x, const float* __restrict__ ct,
                       const float* __restrict__ st, int qoff, float scale) {
  const int gid = blockIdx.x * 256 + threadIdx.x;
  const int r = gid >> 8;
  const int rem = gid & 255;
  const int h = rem >> 5;
  const int i4 = (rem & 31) * 4;
  const int t = r & 2047;
  const size_t o1 = (size_t)r * 4096 + qoff + h * 256 + i4;
  union { ushort4 v; u16 h4[4]; } p1, p2, q1, q2;
  p1.v = *(ushort4*)&x[o1];
  p2.v = *(ushort4*)&x[o1 + 128];
  const float4 c = *(const float4*)&ct[t * 128 + i4];
  const float4 s = *(const float4*)&st[t * 128 + i4];
  const float cc[4] = {c.x, c.y, c.z, c.w};
  const float sn[4] = {s.x, s.y, s.z, s.w};
#pragma unroll
  for (int j = 0; j < 4; ++j) {
    float x1 = b2f(p1.h4[j]), x2 = b2f(p2.h4[j]);
    q1.h4[j] = f2b((x1 * cc[j] - x2 * sn[j]) * scale);
    q2.h4[j] = f2b((x2 * cc[j] + x1 * sn[j]) * scale);
  }
  *(ushort4*)&x[o1] = q1.v;
  *(ushort4*)&x[o1 + 128] = q2.v;
}

// =======================================================================
// GEMM v4 (r8's proven 4-phase deep pipeline, BM=256 for N=4096 projs).
// =======================================================================
template <int BM, int EPI>
__global__ __launch_bounds__(512, 2)
void gemm4(const u16* __restrict__ A, const u16* __restrict__ Bt,
           void* Cout, const float* fsrc, const u16* hsrc,
           int N, int K, int lda, int pm, int pn, int gw) {
  constexpr int MF = BM / 32;
  constexpr int LA = BM / 128;
  constexpr int AH = BM * 64;
  constexpr int BH = 16384;
  constexpr int BUFB = 2 * AH + 2 * BH;
  constexpr int VMC = (BM == 256) ? 8 : 6;
  __shared__ __align__(16) char smem[2 * BUFB];

  const int tid = threadIdx.x;
  const int l = tid & 63, w = tid >> 6;
  const int lr = l & 15, hi = l >> 4;
  const int wm = w >> 2, wn = w & 3;
  const int xcd = blockIdx.x & 7;
  const int jj = blockIdx.x >> 3;
  const int gx = xcd % gw, gy = xcd / gw;
  const int bm = gx * pm + jj / pn;
  const int bn = gy * pn + jj % pn;
  const int nt = K >> 6;

  const int rA = tid >> 2;
  const int chx = (tid & 3) ^ ((tid >> 3) & 3);
  const u16* Ag = A + (size_t)(bm * BM + rA) * lda + chx * 8;
  const u16* Bg = Bt + (size_t)(bn * 256 + rA) * K + chx * 8;
  const int wb = w * 1024;

  int aoff[MF], boff[4];
#pragma unroll
  for (int mf = 0; mf < MF; ++mf) {
    int r = wm * (BM / 2) + mf * 16 + lr;
    aoff[mf] = (r * 4 + (hi ^ ((r >> 1) & 3))) * 16;
  }
#pragma unroll
  for (int nf = 0; nf < 4; ++nf) {
    int r = wn * 64 + nf * 16 + lr;
    boff[nf] = (r * 4 + (hi ^ ((r >> 1) & 3))) * 16;
  }

  f32x4 acc[MF][4];
#pragma unroll
  for (int m = 0; m < MF; ++m)
#pragma unroll
    for (int n = 0; n < 4; ++n) acc[m][n] = (f32x4){0.f, 0.f, 0.f, 0.f};
  u32x4 af[4], bf[4];

#define STA(kt, ks, bb)                                                        \
  { _Pragma("unroll") for (int t = 0; t < LA; ++t)                             \
      async_ld16(Ag + (size_t)t * 128 * lda + (kt) * 64 + (ks) * 32,           \
                 (u16*)(smem + (bb) * BUFB + (ks) * AH + t * 8192 + wb)); }
#define STB(kt, ks, bb)                                                        \
  { _Pragma("unroll") for (int t = 0; t < 2; ++t)                              \
      async_ld16(Bg + (size_t)t * 128 * K + (kt) * 64 + (ks) * 32,             \
                 (u16*)(smem + (bb) * BUFB + 2 * AH + (ks) * BH + t * 8192 + wb)); }
#define RDA(mh, ks, bb)                                                        \
  { _Pragma("unroll") for (int mf = 0; mf < 4; ++mf)                           \
      af[mf] = *(const u32x4*)(smem + (bb) * BUFB + (ks) * AH + aoff[(mh) * 4 + mf]); }
#define RDB(ks, bb)                                                            \
  { _Pragma("unroll") for (int nf = 0; nf < 4; ++nf)                           \
      bf[nf] = *(const u32x4*)(smem + (bb) * BUFB + 2 * AH + (ks) * BH + boff[nf]); }
#define MM(mh)                                                                 \
  { _Pragma("unroll") for (int mf = 0; mf < 4; ++mf)                           \
      _Pragma("unroll") for (int nf = 0; nf < 4; ++nf)                         \
        mfma_bf16(acc[(mh) * 4 + mf][nf], af[mf], bf[nf]); }
#define SB   __builtin_amdgcn_sched_barrier(0)
#define BARR __builtin_amdgcn_s_barrier()
#define VMW  asm volatile("s_waitcnt vmcnt(%0)" :: "n"(VMC) : "memory")

  STA(0, 0, 0); STB(0, 0, 0); STA(0, 1, 0); STB(0, 1, 0);
  STA(1, 0, 1); STB(1, 0, 1);
  SB; VMW; SB; BARR; SB;

  for (int i = 0; i < nt; ++i) {
    const int bb = i & 1, ob = bb ^ 1;
    const int t1 = (i + 1 < nt) ? i + 1 : 0;
    const int t2 = (i + 2 < nt) ? i + 2 : 0;
    RDA(0, 0, bb); RDB(0, bb);
    STA(t1, 1, ob);
    SB; BARR;
    __builtin_amdgcn_s_setprio(1); MM(0); __builtin_amdgcn_s_setprio(0);
    SB; BARR; SB;
    RDA(1, 0, bb);
    STB(t1, 1, ob);
    SB; BARR;
    __builtin_amdgcn_s_setprio(1); MM(1); __builtin_amdgcn_s_setprio(0);
    SB; VMW; BARR; SB;
    RDA(0, 1, bb); RDB(1, bb);
    STA(t2, 0, bb);
    SB; BARR;
    __builtin_amdgcn_s_setprio(1); MM(0); __builtin_amdgcn_s_setprio(0);
    SB; BARR; SB;
    RDA(1, 1, bb);
    STB(t2, 0, bb);
    SB; BARR;
    __builtin_amdgcn_s_setprio(1); MM(1); __builtin_amdgcn_s_setprio(0);
    SB; VMW; BARR; SB;
  }
#undef STA
#undef STB
#undef RDA
#undef RDB
#undef MM
#undef SB
#undef BARR
#undef VMW

  const size_t crow0 = (size_t)(bm * BM + wm * (BM / 2));
  const int ccol0 = bn * 256 + wn * 64;
#pragma unroll
  for (int m = 0; m < MF; ++m)
#pragma unroll
    for (int n = 0; n < 4; ++n)
#pragma unroll
      for (int j2 = 0; j2 < 4; ++j2) {
        size_t r = crow0 + m * 16 + hi * 4 + j2;
        size_t c = (size_t)(ccol0 + n * 16 + lr);
        size_t idx = r * N + c;
        float a = acc[m][n][j2];
        (void)fsrc; (void)hsrc;
        ((u16*)Cout)[idx] = f2b(a);
      }
}

// =======================================================================
// GEMM v6 (r10's proven dbuf + counted-vmcnt, 128x128, 4 blocks/CU,
// 2D XCD patches).  grid = 8*pm*pn, gw*pm == nbm, (8/gw)*pn == nbn.
// EPI: 1 bf16; 2 f32 acc+b2f(hsrc); 3 bf16 silu(acc)*b2f(hsrc); 4 bf16 acc+fsrc
// =======================================================================
template <int EPI>
__global__ __launch_bounds__(256, 4)
void gemm6(const u16* __restrict__ A, const u16* __restrict__ Bt,
           void* Cout, const float* fsrc, const u16* hsrc,
           int N, int K, int lda, int pm, int pn, int gw) {
  __shared__ __align__(16) char smem[2][16384];   // per buf: A 8KB | B 8KB
  const int tid = threadIdx.x;
  const int l = tid & 63, w = tid >> 6;
  const int lr = l & 15, hi = l >> 4;
  const int wm = w >> 1, wn = w & 1;
  const int xcd = blockIdx.x & 7;
  const int jj = blockIdx.x >> 3;
  const int gx = xcd % gw, gy = xcd / gw;
  const int bm = gx * pm + jj / pn;
  const int bn = gy * pn + jj % pn;
  const int nt = K >> 5;

  const u16* Ap[2]; const u16* Bp[2];
#pragma unroll
  for (int t = 0; t < 2; ++t) {
    int s = t * 256 + tid;
    int row = s >> 2, ch = (s & 3) ^ ((s >> 3) & 3);
    Ap[t] = A + (size_t)(bm * 128 + row) * lda + ch * 8;
    Bp[t] = Bt + (size_t)(bn * 128 + row) * K + ch * 8;
  }
  const int dst0 = (0 * 256 + w * 64) * 16;
  const int dst1 = (1 * 256 + w * 64) * 16;

  int aoff[4], boff[4];
#pragma unroll
  for (int f = 0; f < 4; ++f) {
    int ra = wm * 64 + f * 16 + lr;
    aoff[f] = (ra * 4 + (hi ^ ((ra >> 1) & 3))) * 16;
    int rb = wn * 64 + f * 16 + lr;
    boff[f] = 8192 + (rb * 4 + (hi ^ ((rb >> 1) & 3))) * 16;
  }

  f32x4 acc[4][4];
#pragma unroll
  for (int m = 0; m < 4; ++m)
#pragma unroll
    for (int n = 0; n < 4; ++n) acc[m][n] = (f32x4){0.f, 0.f, 0.f, 0.f};

#define SB __builtin_amdgcn_sched_barrier(0)
  auto stage = [&](int i, int s) {
    const int k0 = i * 32;
    async_ld16(Ap[0] + k0, (u16*)(smem[s] + dst0));
    async_ld16(Ap[1] + k0, (u16*)(smem[s] + dst1));
    async_ld16(Bp[0] + k0, (u16*)(smem[s] + 8192 + dst0));
    async_ld16(Bp[1] + k0, (u16*)(smem[s] + 8192 + dst1));
  };

  stage(0, 0);
  SB;
  for (int i = 0; i < nt; ++i) {
    const int cur = i & 1;
    const int ip = (i + 1 < nt) ? i + 1 : 0;     // tail: dead re-stage
    stage(ip, cur ^ 1);
    SB;
    asm volatile("s_waitcnt vmcnt(4)" ::: "memory");   // tile i landed
    SB;
    __builtin_amdgcn_s_barrier();
    SB;
    u32x4 af[4], bf[4];
#pragma unroll
    for (int f = 0; f < 4; ++f) af[f] = *(const u32x4*)(smem[cur] + aoff[f]);
#pragma unroll
    for (int f = 0; f < 4; ++f) bf[f] = *(const u32x4*)(smem[cur] + boff[f]);
    __builtin_amdgcn_s_setprio(1);
#pragma unroll
    for (int m = 0; m < 4; ++m)
#pragma unroll
      for (int n = 0; n < 4; ++n) mfma_bf16(acc[m][n], af[m], bf[n]);
    __builtin_amdgcn_s_setprio(0);
    SB;
    __builtin_amdgcn_s_barrier();    // raw: no vmcnt drain
    SB;
  }
#undef SB

  const size_t crow0 = (size_t)(bm * 128 + wm * 64);
  const int ccol0 = bn * 128 + wn * 64;
#pragma unroll
  for (int m = 0; m < 4; ++m)
#pragma unroll
    for (int n = 0; n < 4; ++n)
#pragma unroll
      for (int j2 = 0; j2 < 4; ++j2) {
        size_t r = crow0 + m * 16 + hi * 4 + j2;
        size_t c = (size_t)(ccol0 + n * 16 + lr);
        size_t idx = r * N + c;
        float a = acc[m][n][j2];
        if (EPI == 1) {
          ((u16*)Cout)[idx] = f2b(a);
        } else if (EPI == 2) {
          ((float*)Cout)[idx] = a + b2f(hsrc[idx]);
        } else if (EPI == 3) {
          float u = b2f(hsrc[idx]);
          ((u16*)Cout)[idx] = f2b(a / (1.0f + expf(-a)) * u);
        } else {
          ((u16*)Cout)[idx] = f2b(a + fsrc[idx]);
        }
      }
}

// =======================================================================
// Chunkwise retention scan (unchanged).
// =======================================================================
#define LGK 264
#define LGC 72
__global__ __launch_bounds__(512)
void retention_kernel(const u16* __restrict__ qk, const u16* __restrict__ kt,
                      const u16* __restrict__ v, u16* __restrict__ o) {
  __shared__ __align__(16) u16 ks[64 * LGK];
  __shared__ __align__(16) u16 stb[32 * LGK];
  __shared__ __align__(16) u16 ktd[256 * LGC];
  __shared__ __align__(16) u16 vts[32 * LGC];
  __shared__ __align__(16) u16 ab[64 * LGC];
  __shared__ float kdt[64];

  const int tid = threadIdx.x;
  const int l = tid & 63, w = tid >> 6;
  const int lr = l & 15, hi = l >> 4;
  const int wr = w >> 1;
  const int eb = w & 1;
  const int bid = blockIdx.x;
  const int g = bid & 15;
  const int sl = bid >> 4;
  const int hh = g & 7;
  const int b = g >> 3;
  const float gamma = 1.0f - exp2f(-5.0f - (float)hh);
  const float lg = log2f(gamma);
  const float cdk = exp2f(64.0f * lg);
  const int e0 = sl * 32;

  if (tid < 64) kdt[tid] = exp2f((float)(63 - tid) * lg);
  __syncthreads();

  f32x4 st[4];
#pragma unroll
  for (int t = 0; t < 4; ++t) st[t] = (f32x4){0.f, 0.f, 0.f, 0.f};

  for (int n = 0; n < 32; ++n) {
    const int row0 = b * 2048 + n * 64;
    const int t0 = n * 64;
#pragma unroll
    for (int t = 0; t < 4; ++t)
#pragma unroll
      for (int j = 0; j < 4; ++j)
        stb[(eb * 16 + hi * 4 + j) * LGK + (wr * 4 + t) * 16 + lr] = f2b(st[t][j]);
    u32x4 qf[8];
#pragma unroll
    for (int kk = 0; kk < 8; ++kk)
      qf[kk] = *(const u32x4*)&qk[(size_t)(row0 + wr * 16 + lr) * 4096 +
                                  hh * 256 + kk * 32 + hi * 8];
#pragma unroll
    for (int p = 0; p < 4; ++p) {
      int idx = p * 512 + tid;
      int c = idx >> 5, s = (idx & 31) * 8;
      *(uint4*)&ks[c * LGK + s] =
          *(const uint4*)&qk[(size_t)(row0 + c) * 4096 + 2048 + hh * 256 + s];
    }
#pragma unroll
    for (int p = 0; p < 4; ++p) {
      int idx = p * 512 + tid;
      int d = idx >> 3, cq = (idx & 7) * 8;
      union { uint4 v4; u16 h[8]; } pk;
      pk.v4 = *(const uint4*)&kt[((size_t)(b * 8 + hh) * 256 + d) * 2048 + t0 + cq];
      union { u16 h[8]; uint4 v4; } wo;
#pragma unroll
      for (int j2 = 0; j2 < 8; ++j2)
        wo.h[j2] = f2b(b2f(pk.h[j2]) * kdt[cq + j2]);
      *(uint4*)&ktd[d * LGC + cq] = wo.v4;
    }
#pragma unroll
    for (int p = 0; p < 4; ++p) {
      int c = (tid >> 5) + p * 16, e = tid & 31;
      vts[e * LGC + c] = v[(size_t)(row0 + c) * 4096 + hh * 512 + e0 + e];
    }
    __syncthreads();

    f32x4 att[2];
    att[0] = (f32x4){0.f, 0.f, 0.f, 0.f};
    att[1] = (f32x4){0.f, 0.f, 0.f, 0.f};
#pragma unroll
    for (int kk = 0; kk < 8; ++kk) {
#pragma unroll
      for (int jf = 0; jf < 2; ++jf) {
        u32x4 bb = *(const u32x4*)&ks[(eb * 32 + jf * 16 + lr) * LGK + kk * 32 + hi * 8];
        mfma_bf16(att[jf], qf[kk], bb);
      }
    }
#pragma unroll
    for (int jf = 0; jf < 2; ++jf)
#pragma unroll
      for (int j = 0; j < 4; ++j) {
        int i = wr * 16 + hi * 4 + j;
        int jc = eb * 32 + jf * 16 + lr;
        float mv = (i >= jc) ? exp2f((float)(i - jc) * lg) : 0.0f;
        ab[i * LGC + jc] = f2b(att[jf][j] * mv);
      }
    f32x4 occ = (f32x4){0.f, 0.f, 0.f, 0.f};
#pragma unroll
    for (int kk = 0; kk < 8; ++kk) {
      u32x4 bb = *(const u32x4*)&stb[(eb * 16 + lr) * LGK + kk * 32 + hi * 8];
      mfma_bf16(occ, qf[kk], bb);
    }
    __syncthreads();

#pragma unroll
    for (int j = 0; j < 4; ++j) {
      int i = wr * 16 + hi * 4 + j;
      occ[j] *= exp2f((float)(i + 1) * lg);
    }
#pragma unroll
    for (int kk = 0; kk < 2; ++kk) {
      u32x4 aa = *(const u32x4*)&ab[(wr * 16 + lr) * LGC + kk * 32 + hi * 8];
      u32x4 bb = *(const u32x4*)&vts[(eb * 16 + lr) * LGC + kk * 32 + hi * 8];
      mfma_bf16(occ, aa, bb);
    }
#pragma unroll
    for (int j = 0; j < 4; ++j) {
      int i = wr * 16 + hi * 4 + j;
      o[(size_t)(row0 + i) * 4096 + hh * 512 + e0 + eb * 16 + lr] = f2b(occ[j]);
    }
#pragma unroll
    for (int t = 0; t < 4; ++t) {
      st[t][0] *= cdk; st[t][1] *= cdk; st[t][2] *= cdk; st[t][3] *= cdk;
    }
#pragma unroll
    for (int kk = 0; kk < 2; ++kk) {
      u32x4 aa = *(const u32x4*)&vts[(eb * 16 + lr) * LGC + kk * 32 + hi * 8];
#pragma unroll
      for (int t = 0; t < 4; ++t) {
        u32x4 bb = *(const u32x4*)&ktd[((wr * 4 + t) * 16 + lr) * LGC + kk * 32 + hi * 8];
        mfma_bf16(st[t], aa, bb);
      }
    }
    __syncthreads();
  }
}

// =======================================================================
// Gated head-RMSNorm IN PLACE on o (bf16)
// =======================================================================
__global__ __launch_bounds__(64)
void gating_kernel(u16* __restrict__ o, const u16* __restrict__ g,
                   const float* __restrict__ gnw) {
  const int blk = blockIdx.x;
  const size_t base = (size_t)blk * 512;
  const int l = threadIdx.x;
  union { uint4 v4; u16 h[8]; } ov, gv;
  ov.v4 = *(const uint4*)&o[base + l * 8];
  float x[8];
  float ss = 0.f;
#pragma unroll
  for (int j = 0; j < 8; ++j) { x[j] = b2f(ov.h[j]); ss += x[j] * x[j]; }
#pragma unroll
  for (int m = 32; m; m >>= 1) ss += __shfl_xor(ss, m);
  const float sc = rsqrtf(ss * (1.0f / 512.0f) + 1e-6f);
  gv.v4 = *(const uint4*)&g[base + l * 8];
  union { u16 h[8]; uint4 v4; } ou;
#pragma unroll
  for (int j = 0; j < 8; ++j) {
    float gvf = b2f(gv.h[j]);
    float sig = 1.0f / (1.0f + expf(-gvf));
    ou.h[j] = f2b(x[j] * sc * gnw[l * 8 + j] * gvf * sig);
  }
  *(uint4*)&o[base + l * 8] = ou.v4;
}

// =======================================================================
extern "C" void kernel_launch(void* const* d_in, const int* in_sizes, int n_in,
                              void* d_out, int out_size, void* d_ws, size_t ws_size,
                              hipStream_t stream) {
  (void)in_sizes; (void)n_in; (void)out_size; (void)ws_size;
  const float* hidden      = (const float*)d_in[0];
  const float* attn_norm_w = (const float*)d_in[1];
  const float* q_w         = (const float*)d_in[2];
  const float* k_w         = (const float*)d_in[3];
  const float* v_w         = (const float*)d_in[4];
  const float* g_w         = (const float*)d_in[5];
  const float* o_w         = (const float*)d_in[6];
  const float* gnorm_w     = (const float*)d_in[7];
  const float* mlp_norm_w  = (const float*)d_in[8];
  const float* gate_w      = (const float*)d_in[9];
  const float* down_w      = (const float*)d_in[10];
  float* outp = (float*)d_out;

  char* ws = (char*)d_ws;
  size_t off = 0;
  auto alloc = [&](size_t bytes) -> char* {
    char* p = ws + off;
    off += (bytes + 255) & ~(size_t)255;
    return p;
  };
  u16*   W    = (u16*)alloc(23068672ULL);   // weight scratch (kt aliases)
  float* ctab = (float*)alloc(1048576ULL);
  float* stab = (float*)alloc(1048576ULL);
  u16*   hb   = (u16*)alloc(16777216ULL);
  u16*   qkb  = (u16*)alloc(33554432ULL);   // [4096][4096] = q|k combined
  u16*   vb   = (u16*)alloc(33554432ULL);
  u16*   gb   = (u16*)alloc(33554432ULL);
  u16*   ob   = (u16*)alloc(33554432ULL);
  u16*   resb = (u16*)alloc(16777216ULL);
  u16*   ybU  = qkb;   // [4096][5632] over qkb+vb (dead post-retention)
  u16*   kt   = W;     // [16][256][2048] while W idle (rope -> retention)

  rope_table_kernel<<<1024, 256, 0, stream>>>(ctab, stab);
  rmsnorm_cast_kernel<<<4096, 256, 0, stream>>>(hidden, attn_norm_w, hb);

  // QK combined projection: W = [qwT ; kwT], N=4096 (gemm4-256, grid 256)
  transpose_cast_kernel<<<1024, 256, 0, stream>>>(q_w, W, 2048, 2048, 2048);
  transpose_cast_kernel<<<1024, 256, 0, stream>>>(k_w, W + 2048ULL * 2048, 2048, 2048, 2048);
  gemm4<256, 1><<<256, 512, 0, stream>>>(hb, W, (void*)qkb, nullptr, nullptr,
                                         4096, 2048, 2048, 8, 4, 2);
  // V projection
  transpose_cast_kernel<<<2048, 256, 0, stream>>>(v_w, W, 2048, 4096, 4096);
  gemm4<256, 1><<<256, 512, 0, stream>>>(hb, W, (void*)vb, nullptr, nullptr,
                                         4096, 2048, 2048, 8, 4, 2);
  // G projection
  transpose_cast_kernel<<<2048, 256, 0, stream>>>(g_w, W, 2048, 4096, 4096);
  gemm4<256, 1><<<256, 512, 0, stream>>>(hb, W, (void*)gb, nullptr, nullptr,
                                         4096, 2048, 2048, 8, 4, 2);

  // RoPE (+ q scale 1/16), then k -> kt
  rope_apply_kernel<<<4096, 256, 0, stream>>>(qkb, ctab, stab, 0, 0.0625f);
  rope_apply_kernel<<<4096, 256, 0, stream>>>(qkb, ctab, stab, 2048, 1.0f);
  transpose_k_kernel<<<2048, 256, 0, stream>>>(qkb, kt);

  // Retention scan -> ob
  retention_kernel<<<256, 512, 0, stream>>>(qkb, kt, vb, ob);

  // Gated head RMSNorm in place on ob
  gating_kernel<<<32768, 64, 0, stream>>>(ob, gb, gnorm_w);

  // O projection + residual(hidden) -> resb (gemm6 2D patches: nbm=32,
  // nbn=16 -> pm=16, pn=4, gw=2; grid 512)
  transpose_cast_kernel<<<2048, 256, 0, stream>>>(o_w, W, 4096, 2048, 2048);
  gemm6<4><<<512, 256, 0, stream>>>(ob, W, (void*)resb, hidden, nullptr,
                                    2048, 4096, 4096, 16, 4, 2);

  // MLP RMSNorm
  rmsnorm_bf16_kernel<<<4096, 256, 0, stream>>>(resb, mlp_norm_w, hb);

  // Up-half GEMM -> ybU (gemm6: nbm=32, nbn=44 -> pm=16, pn=11, gw=2;
  // grid 1408)
  transpose_cast_kernel<<<2816, 256, 0, stream>>>(gate_w + 5632, W, 2048, 5632, 11264);
  gemm6<1><<<1408, 256, 0, stream>>>(hb, W, (void*)ybU, nullptr, nullptr,
                                     5632, 2048, 2048, 16, 11, 2);
  // Gate-half GEMM fused SwiGLU in place over ybU
  transpose_cast_kernel<<<2816, 256, 0, stream>>>(gate_w, W, 2048, 5632, 11264);
  gemm6<3><<<1408, 256, 0, stream>>>(hb, W, (void*)ybU, nullptr, ybU,
                                     5632, 2048, 2048, 16, 11, 2);

  // Down projection + residual(resb) -> d_out (gemm6: nbm=32, nbn=16 ->
  // pm=16, pn=4, gw=2; grid 512)
  transpose_cast_kernel<<<2816, 256, 0, stream>>>(down_w, W, 5632, 2048, 2048);
  gemm6<2><<<512, 256, 0, stream>>>(ybU, W, (void*)outp, nullptr, resb,
                                    2048, 5632, 5632, 16, 4, 2);
}